// Round 14
// baseline (335.218 us; speedup 1.0000x reference)
//
#include <hip/hip_runtime.h>

// Batched 16-qubit statevector sim, 64-VGPR-budget edition (v2: LDS-traffic cut).
// One 1024-thread block per batch element. Amp bits: [15:12]=wave, [11:6]=lane,
// [5]=SPLIT (reg half vs LDS half), [4:0]=slot. Qubit q <-> amp bit (15-q).
//
// Measured: R2..R11: compiler hard-caps VGPR at 64; R12 split-state rewrite
// eliminated spill (720MB->18MB HBM, 354->278us) but is LDS-pipe-bound
// (~750 b64-equiv LDS ops/thread/layer, VALUBusy 34%).
// R13 changes (target ~224 b64-eq/layer, ~3.3x less LDS; unmeasured r13 —
// infra timeout — resubmitted after paper-verifying SIG direction and the
// physical-identity wave-map argument):
//  (1) P1+P2 fused: LDS half loaded once per 16-float chunk; reg-bit RYs AND
//      all 6 lane-bit RYs (shfl_xor) applied in registers; stored once.
//  (2) P3 transposed: each thread reads a 16-wave column (2 slots), applies
//      the 4 wave-RY butterflies in registers (physical masks {1,2,4,8}),
//      and applies the wave CNOT staircase for FREE via the Gray permutation
//      SIG(v)=v^(v>>1) on the READ index of the writeback (out[w]=rr[SIG[w]];
//      staircase composite T has T^-1 = SIG, verified). Wave relabel tables
//      eliminated; (12,11) ctrl becomes physical wv&1. Barriers 10->4/layer.
//      Known cost: column access = 4-way bank conflict (stride 34 = 2 mod 32).
// Unchanged from measured-correct R12: lane relabels (LM/LS/TM11/LC), init,
// SWAP1/SWAP2 AQ/CHI reg-cascade fold, (6,5)' conjugated boundary CNOT,
// output location.

__device__ __constant__ unsigned char LM[4][6] = {
  {0x01,0x02,0x04,0x08,0x10,0x20},
  {0x01,0x03,0x06,0x0C,0x18,0x30},
  {0x01,0x02,0x05,0x0A,0x14,0x28},
  {0x01,0x03,0x07,0x0F,0x1E,0x3C}};
__device__ __constant__ unsigned char LS[4][6] = {
  {0x01,0x02,0x04,0x08,0x10,0x20},
  {0x3F,0x3E,0x3C,0x38,0x30,0x20},
  {0x15,0x2A,0x14,0x28,0x10,0x20},
  {0x33,0x26,0x0C,0x18,0x30,0x20}};
__device__ __constant__ unsigned char TM11[4] = {0x20,0x30,0x28,0x3C};
__device__ __constant__ unsigned char LC[4]   = {0x3F,0x15,0x33,0x11};

// Wave CNOT staircase composite (T^-1 = Gray): SIG[v] = v ^ (v>>1).
static constexpr int SIG[16] = {0,1,3,2,6,7,5,4,12,13,15,14,10,11,9,8};
// AQ[q] = gray(q^31): SWAP2 pairing; CHI[i]: register rename (CHI∘AQ = T5).
static constexpr int AQ[32] = {
  16,17,19,18,22,23,21,20,28,29,31,30,26,27,25,24,
   8, 9,11,10,14,15,13,12, 4, 5, 7, 6, 2, 3, 1, 0};
static constexpr int CHI[32] = {
  21,20,23,22,16,17,18,19,31,30,29,28,26,27,24,25,
   0, 1, 2, 3, 5, 4, 7, 6,10,11, 8, 9,15,14,13,12};

__global__ __launch_bounds__(1024)
void qsim_kernel(const float* __restrict__ x, const float* __restrict__ wts,
                 float* __restrict__ out) {
  __shared__ float  Lbuf[16][64][34];   // 139264 B; pad 34 -> f2-aligned rows
  __shared__ float2 ang[80];            // [0..15]: x RYs; [16+16l+q]: layer l

  const int tid   = threadIdx.x;
  const int lane  = tid & 63;
  const int wv    = tid >> 6;
  const int batch = blockIdx.x;

  if (tid < 80) {
    float th = (tid < 16) ? x[batch * 16 + tid] : wts[tid - 16];
    float s, c;
    sincosf(0.5f * th, &s, &c);
    ang[tid] = make_float2(c, s);
  }
  __syncthreads();

  float st[32];
  float2* Lf2 = (float2*)&Lbuf[wv][lane][0];

  // ---- init: product state; reg half gets c(q10), LDS half s(q10) ----
  {
    float f = 1.0f;
#pragma unroll
    for (int b = 0; b < 4; ++b) { float2 a = ang[3 - b]; f *= ((wv   >> b) & 1) ? a.y : a.x; }
#pragma unroll
    for (int e = 0; e < 6; ++e) { float2 a = ang[9 - e]; f *= ((lane >> e) & 1) ? a.y : a.x; }
    st[0] = f;
#pragma unroll
    for (int k = 0; k < 5; ++k) {
      float2 a = ang[15 - k];
      const int m = 1 << k;
#pragma unroll
      for (int r = 0; r < 16; ++r) if (r < m) {
        st[r + m] = st[r] * a.y;
        st[r]     = st[r] * a.x;
      }
    }
    float2 a10 = ang[10];
#pragma unroll
    for (int p = 0; p < 16; ++p) {
      Lf2[p] = make_float2(st[2*p] * a10.y, st[2*p+1] * a10.y);
      st[2*p] *= a10.x; st[2*p+1] *= a10.x;
    }
  }

  for (int l = 0; l < 4; ++l) {
    const float2* la = &ang[16 + l * 16];

    // ---- P1+P2 fused: reg-bit RYs b0..b3 + b5 + all 6 lane RYs, chunked ----
#pragma unroll
    for (int c = 0; c < 2; ++c) {
      float t[16];
#pragma unroll
      for (int p = 0; p < 8; ++p) { float2 v = Lf2[8*c + p]; t[2*p] = v.x; t[2*p+1] = v.y; }
#pragma unroll
      for (int k = 0; k < 4; ++k) {
        const float2 a = la[15 - k];
        const int m = 1 << k;
#pragma unroll
        for (int r = 0; r < 16; ++r) if (!(r & m)) {
          float u0 = t[r], u1 = t[r + m];
          t[r]     = a.x*u0 - a.y*u1;
          t[r + m] = a.y*u0 + a.x*u1;
          float v0 = st[16*c + r], v1 = st[16*c + r + m];
          st[16*c + r]     = a.x*v0 - a.y*v1;
          st[16*c + r + m] = a.y*v0 + a.x*v1;
        }
      }
      { const float2 a5 = la[10];   // split-bit RY (qubit 10)
#pragma unroll
        for (int j = 0; j < 16; ++j) {
          float v0 = st[16*c + j], v1 = t[j];
          st[16*c + j] = a5.x*v0 - a5.y*v1;
          t[j]         = a5.y*v0 + a5.x*v1;
        } }
      // lane RYs (qubits 4..9) on both t[] and st-chunk via shfl_xor
      for (int e = 0; e < 6; ++e) {
        const float2 a = la[9 - e];
        const int m = LM[l][e];
        const float sg = (__popc(lane & LS[l][e]) & 1) ? a.y : -a.y;
#pragma unroll
        for (int j = 0; j < 16; ++j) {
          float o = __shfl_xor(t[j], m);
          t[j] = fmaf(sg, o, a.x * t[j]);
          float o2 = __shfl_xor(st[16*c + j], m);
          st[16*c + j] = fmaf(sg, o2, a.x * st[16*c + j]);
        }
      }
#pragma unroll
      for (int p = 0; p < 8; ++p) Lf2[8*c + p] = make_float2(t[2*p], t[2*p+1]);
    }
    { const float2 a = la[11];   // bit4 RY (qubit 11): crosses chunk boundary
#pragma unroll
      for (int r = 0; r < 16; ++r) {
        float v0 = st[r], v1 = st[r + 16];
        st[r]      = a.x*v0 - a.y*v1;
        st[r + 16] = a.y*v0 + a.x*v1;
      }
#pragma unroll
      for (int p = 0; p < 8; ++p) {
        float2 A = Lf2[p], B = Lf2[p + 8];
        Lf2[p]     = make_float2(a.x*A.x - a.y*B.x, a.x*A.y - a.y*B.y);
        Lf2[p + 8] = make_float2(a.y*A.x + a.x*B.x, a.y*A.y + a.x*B.y);
      } }

    // ---- P3: transposed wave RYs + staircase sigma, 2 rounds ----
#pragma unroll
    for (int round = 0; round < 2; ++round) {
      __syncthreads();                       // prior writes visible
#pragma unroll
      for (int sl = 0; sl < 2; ++sl) {
        const int slot = 2*wv + sl;          // this thread's slot column
        float rr[16];
#pragma unroll
        for (int w = 0; w < 16; ++w) rr[w] = Lbuf[w][lane][slot];
#pragma unroll
        for (int b = 0; b < 4; ++b) {        // wave-bit RYs, physical masks
          const float2 a = la[3 - b];
          const int m = 1 << b;
#pragma unroll
          for (int w = 0; w < 16; ++w) if (!(w & m)) {
            float lo = rr[w], hi = rr[w + m];
            rr[w]     = a.x*lo - a.y*hi;
            rr[w + m] = a.y*lo + a.x*hi;
          }
        }
#pragma unroll
        for (int w = 0; w < 16; ++w)         // wave CNOT staircase: free
          Lbuf[w][lane][slot] = rr[SIG[w]];
      }
      __syncthreads();
      if (round == 0) {
        // SWAP1: plain st <-> L
#pragma unroll
        for (int p = 0; p < 16; ++p) {
          float2 r = Lf2[p];
          Lf2[p] = make_float2(st[2*p], st[2*p+1]);
          st[2*p] = r.x; st[2*p+1] = r.y;
        }
      } else {
        // SWAP2 + reg-cascade fold (float2: AQ keeps f2-pairs adjacent)
#pragma unroll
        for (int p = 0; p < 16; ++p) {
          float2 r = Lf2[p];
          Lf2[p] = make_float2(st[AQ[2*p]], st[AQ[2*p+1]]);
          st[AQ[2*p]] = r.x; st[AQ[2*p+1]] = r.y;
        }
        float ns[32];
#pragma unroll
        for (int i = 0; i < 32; ++i) ns[CHI[i]] = st[i];
#pragma unroll
        for (int i = 0; i < 32; ++i) st[i] = ns[i];
      }
    }

    // ---- P4: CNOT boundary moves (same-wave only; lockstep, no barriers) ----
    { const int tm = TM11[l];                // (12,11): ctrl = physical wv bit0
      if (wv & 1) {
#pragma unroll
        for (int r = 0; r < 32; ++r) st[r] = __shfl_xor(st[r], tm);
        const float2* Pf2 = (const float2*)&Lbuf[wv][lane ^ tm][0];
#pragma unroll
        for (int p = 0; p < 16; ++p) { float2 v = Pf2[p]; Lf2[p] = v; }
      } }
    { if (__popc(lane & LC[l]) & 1) {        // (6,5)' conjugated: st[k]<->L[k^31]
#pragma unroll
        for (int p = 0; p < 16; ++p) {
          float2 v = Lf2[p ^ 15];
          Lf2[p ^ 15] = make_float2(st[2*p+1], st[2*p]);
          st[2*p] = v.y; st[2*p+1] = v.x;
        }
      } }
  }

  // Output: lambda(0)=0 and canonical slots -> logical 0..15 = st[0..15]@tid0.
  if (tid == 0) {
#pragma unroll
    for (int j = 0; j < 16; ++j) out[batch * 16 + j] = st[j];
  }
}

extern "C" void kernel_launch(void* const* d_in, const int* in_sizes, int n_in,
                              void* d_out, int out_size, void* d_ws, size_t ws_size,
                              hipStream_t stream) {
  const float* x   = (const float*)d_in[0];
  const float* wts = (const float*)d_in[1];
  float* out = (float*)d_out;
  const int batch = in_sizes[0] / 16;   // 512
  qsim_kernel<<<dim3(batch), dim3(1024), 0, stream>>>(x, wts, out);
}